// Round 10
// baseline (300.216 us; speedup 1.0000x reference)
//
#include <hip/hip_runtime.h>
#include <hip/hip_bf16.h>
#include <cstdint>
#include <cstddef>

// Problem: B=64, L=2048, E=1024, A=512
#define BB   64
#define LL   2048
#define ED   1024
#define AD   512
#define BM   64           // l-rows per block (block = 64 x 512, 8 waves of 64x64)
#define NCH  (LL / BM)    // 32 chunks per batch row
#define KS2  16           // 16 K-steps of BK=64

typedef short  short8  __attribute__((ext_vector_type(8)));
typedef float  f32x4   __attribute__((ext_vector_type(4)));

__device__ __forceinline__ unsigned short f2bf(float x) {
  unsigned u = __float_as_uint(x);
  u += 0x7FFFu + ((u >> 16) & 1u);
  return (unsigned short)(u >> 16);
}

// pack 8 fp32 -> 8 bf16 (RNE) via v_cvt_pk_bf16_f32
__device__ __forceinline__ short8 cvt8(f32x4 lo, f32x4 hi) {
  union { short8 s; unsigned u[4]; } r;
  asm("v_cvt_pk_bf16_f32 %0, %1, %2" : "=v"(r.u[0]) : "v"(lo[0]), "v"(lo[1]));
  asm("v_cvt_pk_bf16_f32 %0, %1, %2" : "=v"(r.u[1]) : "v"(lo[2]), "v"(lo[3]));
  asm("v_cvt_pk_bf16_f32 %0, %1, %2" : "=v"(r.u[2]) : "v"(hi[0]), "v"(hi[1]));
  asm("v_cvt_pk_bf16_f32 %0, %1, %2" : "=v"(r.u[3]) : "v"(hi[2]), "v"(hi[3]));
  return r.s;
}

// ---------------- kernel 0: prep ----------------
// blocks 0..63   : dec_proj row b = dec[b] @ W_dec + b_dec
// blocks 64..191 : pack W_enc fp32 -> bf16 in frag-contiguous layout:
//   o = ks*16384 + cblk*512 + kg*128 + r*8 + j ; k = ks*32+kg*8+j, col = cblk*16+r
__global__ __launch_bounds__(512) void prep_kernel(
    const float* __restrict__ W_enc, const float* __restrict__ dec,
    const float* __restrict__ W_dec, const float* __restrict__ b_dec,
    unsigned short* __restrict__ Wb, float* __restrict__ dp) {
  const int blk = blockIdx.x, t = threadIdx.x;
  if (blk < BB) {
    const float* drow = dec + blk * ED;
    float a0 = 0.f, a1 = 0.f, a2 = 0.f, a3 = 0.f;
    for (int k = 0; k < ED; k += 4) {
      a0 = fmaf(drow[k],     W_dec[(k)     * AD + t], a0);
      a1 = fmaf(drow[k + 1], W_dec[(k + 1) * AD + t], a1);
      a2 = fmaf(drow[k + 2], W_dec[(k + 2) * AD + t], a2);
      a3 = fmaf(drow[k + 3], W_dec[(k + 3) * AD + t], a3);
    }
    dp[blk * AD + t] = (a0 + a1) + (a2 + a3) + b_dec[t];
  } else {
    const int base = (blk - BB) * 4096;
#pragma unroll
    for (int ii = 0; ii < 8; ii++) {
      const int o    = base + ii * 512 + t;
      const int ks   = o >> 14;
      const int cblk = (o >> 9) & 31;
      const int kg   = (o >> 7) & 3;
      const int r    = (o >> 3) & 15;
      const int j    = o & 7;
      const int k    = ks * 32 + kg * 8 + j;
      const int c    = cblk * 16 + r;
      Wb[o] = f2bf(W_enc[k * AD + c]);
    }
  }
}

// ---------------- kernel 1: fused GEMM + tanh-score + softmax partials ----------
// grid (NCH=32, BB), 512 threads = 8 waves (1M x 8N), wave tile 64 x 64, BK=64.
// LITTLE'S-LAW DESIGN: A loads 32 contiguous B/thread/step (2xf32x4), 1 iter deep
// -> ~32 KB in flight/CU (2 blocks). B has NO LDS: frags read straight from the
// L2-resident frag-contiguous Wb. LDS = A bf16 dbuf only (16 KB/block) ->
// 2 blocks/CU at VGPR<=128 (__launch_bounds__(512,4), acc[4][4]=64).
// Counted waits only: cvt auto-waits vmcnt(6); end-of-iter vmcnt(2); raw barrier.
__global__ __launch_bounds__(512, 4) void fused_kernel(
    const float* __restrict__ sem, const unsigned short* __restrict__ Wb,
    const float* __restrict__ dp, const float* __restrict__ b_enc,
    const float* __restrict__ Wf,
    float* __restrict__ raw_scores,
    float* __restrict__ ws_ms, float* __restrict__ ws_o) {

  __shared__ unsigned short Ab[2][4096];     // [buf][s(2)][rblk(4)][kg(4)][16][8] 16 KB

  const int t    = threadIdx.x;
  const int lane = t & 63;
  const int wn   = t >> 6;      // 0..7 col eighth (64 cols each)
  const int b    = blockIdx.y;
  const int chunk= blockIdx.x;
  const int l0   = chunk * BM;

  // A staging: thread -> (row srow, 8-float seg skg); 2 f32x4 loads, 1 ds_write_b128
  const int srow = t >> 3;      // 0..63
  const int skg  = t & 7;       // 0..7 (k = skg*8 .. +7 within the 64-k step)
  const float* aptr = sem + ((size_t)(b * LL + l0 + srow)) * ED + skg * 8;
  // element (s=skg>>2, rblk=srow>>4, kg=skg&3, r=srow&15, j)
  const int awr = (skg >> 2) * 2048 + (srow >> 4) * 512 + (skg & 3) * 128 + (srow & 15) * 8;

  // frag read bases
  const int arow = lane & 15;
  const int akg  = lane >> 4;
  const int afr  = lane * 8;                   // + h*2048 + mf*512 (A in Ab)
  const unsigned short* wbb = Wb + wn * 2048 + lane * 8;   // + ks32*16384 + nf*512

  f32x4 acc[4][4];
#pragma unroll
  for (int i = 0; i < 4; i++)
#pragma unroll
    for (int j = 0; j < 4; j++) acc[i][j] = (f32x4)0.f;

  // ---- prologue: A(0)->cvt->Ab[0]; A(1)->qA (stays in flight) ----
  f32x4 tA0 = *(const f32x4*)(aptr);
  f32x4 tA1 = *(const f32x4*)(aptr + 4);
  f32x4 qA0 = *(const f32x4*)(aptr + 64);
  f32x4 qA1 = *(const f32x4*)(aptr + 68);
  f32x4 pA0, pA1;
  *(short8*)&Ab[0][awr] = cvt8(tA0, tA1);      // auto-waits tA; qA stays in flight
  asm volatile("s_waitcnt lgkmcnt(0)" ::: "memory");
  __builtin_amdgcn_sched_barrier(0);
  __builtin_amdgcn_s_barrier();

  // ITER(ks): B-half0 loads (L2) -> A(ks+2) loads -> cvt A(ks+1)->Ab[nb] (auto
  // vmcnt(6)) -> av half0 + 16 MFMA -> B-half1 -> av half1 + 16 MFMA ->
  // vmcnt(2) lgkmcnt(0) (A loads stay in flight) -> barrier.
#define ITER(ks, CA0, CA1, LA0, LA1)                                               \
  {                                                                                \
    const int cb = (ks) & 1, nb = ((ks) + 1) & 1;                                  \
    const unsigned short* wq = wbb + (size_t)(2 * (ks)) * 16384;                   \
    short8 bv0, bv1, bv2, bv3;                                                     \
    bv0 = *(const short8*)(wq);                                                    \
    bv1 = *(const short8*)(wq + 512);                                              \
    bv2 = *(const short8*)(wq + 1024);                                             \
    bv3 = *(const short8*)(wq + 1536);                                             \
    if ((ks) + 2 < KS2) {                                                          \
      const float* ap = aptr + ((ks) + 2) * 64;                                    \
      LA0 = *(const f32x4*)(ap);                                                   \
      LA1 = *(const f32x4*)(ap + 4);                                               \
    }                                                                              \
    if ((ks) + 1 < KS2)                                                            \
      *(short8*)&Ab[nb][awr] = cvt8(CA0, CA1);  /* auto vmcnt: bv+LA stay */       \
    short8 av0 = *(const short8*)&Ab[cb][afr];                                     \
    short8 av1 = *(const short8*)&Ab[cb][afr + 512];                               \
    short8 av2 = *(const short8*)&Ab[cb][afr + 1024];                              \
    short8 av3 = *(const short8*)&Ab[cb][afr + 1536];                              \
    __builtin_amdgcn_s_setprio(1);                                                 \
    acc[0][0] = __builtin_amdgcn_mfma_f32_16x16x32_bf16(av0, bv0, acc[0][0],0,0,0);\
    acc[1][0] = __builtin_amdgcn_mfma_f32_16x16x32_bf16(av1, bv0, acc[1][0],0,0,0);\
    acc[2][0] = __builtin_amdgcn_mfma_f32_16x16x32_bf16(av2, bv0, acc[2][0],0,0,0);\
    acc[3][0] = __builtin_amdgcn_mfma_f32_16x16x32_bf16(av3, bv0, acc[3][0],0,0,0);\
    acc[0][1] = __builtin_amdgcn_mfma_f32_16x16x32_bf16(av0, bv1, acc[0][1],0,0,0);\
    acc[1][1] = __builtin_amdgcn_mfma_f32_16x16x32_bf16(av1, bv1, acc[1][1],0,0,0);\
    acc[2][1] = __builtin_amdgcn_mfma_f32_16x16x32_bf16(av2, bv1, acc[2][1],0,0,0);\
    acc[3][1] = __builtin_amdgcn_mfma_f32_16x16x32_bf16(av3, bv1, acc[3][1],0,0,0);\
    acc[0][2] = __builtin_amdgcn_mfma_f32_16x16x32_bf16(av0, bv2, acc[0][2],0,0,0);\
    acc[1][2] = __builtin_amdgcn_mfma_f32_16x16x32_bf16(av1, bv2, acc[1][2],0,0,0);\
    acc[2][2] = __builtin_amdgcn_mfma_f32_16x16x32_bf16(av2, bv2, acc[2][2],0,0,0);\
    acc[3][2] = __builtin_amdgcn_mfma_f32_16x16x32_bf16(av3, bv2, acc[3][2],0,0,0);\
    acc[0][3] = __builtin_amdgcn_mfma_f32_16x16x32_bf16(av0, bv3, acc[0][3],0,0,0);\
    acc[1][3] = __builtin_amdgcn_mfma_f32_16x16x32_bf16(av1, bv3, acc[1][3],0,0,0);\
    acc[2][3] = __builtin_amdgcn_mfma_f32_16x16x32_bf16(av2, bv3, acc[2][3],0,0,0);\
    acc[3][3] = __builtin_amdgcn_mfma_f32_16x16x32_bf16(av3, bv3, acc[3][3],0,0,0);\
    __builtin_amdgcn_s_setprio(0);                                                 \
    bv0 = *(const short8*)(wq + 16384);                                            \
    bv1 = *(const short8*)(wq + 16384 + 512);                                      \
    bv2 = *(const short8*)(wq + 16384 + 1024);                                     \
    bv3 = *(const short8*)(wq + 16384 + 1536);                                     \
    av0 = *(const short8*)&Ab[cb][afr + 2048];                                     \
    av1 = *(const short8*)&Ab[cb][afr + 2560];                                     \
    av2 = *(const short8*)&Ab[cb][afr + 3072];                                     \
    av3 = *(const short8*)&Ab[cb][afr + 3584];                                     \
    __builtin_amdgcn_s_setprio(1);                                                 \
    acc[0][0] = __builtin_amdgcn_mfma_f32_16x16x32_bf16(av0, bv0, acc[0][0],0,0,0);\
    acc[1][0] = __builtin_amdgcn_mfma_f32_16x16x32_bf16(av1, bv0, acc[1][0],0,0,0);\
    acc[2][0] = __builtin_amdgcn_mfma_f32_16x16x32_bf16(av2, bv0, acc[2][0],0,0,0);\
    acc[3][0] = __builtin_amdgcn_mfma_f32_16x16x32_bf16(av3, bv0, acc[3][0],0,0,0);\
    acc[0][1] = __builtin_amdgcn_mfma_f32_16x16x32_bf16(av0, bv1, acc[0][1],0,0,0);\
    acc[1][1] = __builtin_amdgcn_mfma_f32_16x16x32_bf16(av1, bv1, acc[1][1],0,0,0);\
    acc[2][1] = __builtin_amdgcn_mfma_f32_16x16x32_bf16(av2, bv1, acc[2][1],0,0,0);\
    acc[3][1] = __builtin_amdgcn_mfma_f32_16x16x32_bf16(av3, bv1, acc[3][1],0,0,0);\
    acc[0][2] = __builtin_amdgcn_mfma_f32_16x16x32_bf16(av0, bv2, acc[0][2],0,0,0);\
    acc[1][2] = __builtin_amdgcn_mfma_f32_16x16x32_bf16(av1, bv2, acc[1][2],0,0,0);\
    acc[2][2] = __builtin_amdgcn_mfma_f32_16x16x32_bf16(av2, bv2, acc[2][2],0,0,0);\
    acc[3][2] = __builtin_amdgcn_mfma_f32_16x16x32_bf16(av3, bv2, acc[3][2],0,0,0);\
    acc[0][3] = __builtin_amdgcn_mfma_f32_16x16x32_bf16(av0, bv3, acc[0][3],0,0,0);\
    acc[1][3] = __builtin_amdgcn_mfma_f32_16x16x32_bf16(av1, bv3, acc[1][3],0,0,0);\
    acc[2][3] = __builtin_amdgcn_mfma_f32_16x16x32_bf16(av2, bv3, acc[2][3],0,0,0);\
    acc[3][3] = __builtin_amdgcn_mfma_f32_16x16x32_bf16(av3, bv3, acc[3][3],0,0,0);\
    __builtin_amdgcn_s_setprio(0);                                                 \
    if ((ks) + 2 < KS2) {                                                          \
      asm volatile("s_waitcnt vmcnt(2) lgkmcnt(0)" ::: "memory");                  \
    } else {                                                                       \
      asm volatile("s_waitcnt vmcnt(0) lgkmcnt(0)" ::: "memory");                  \
    }                                                                              \
    __builtin_amdgcn_sched_barrier(0);                                             \
    __builtin_amdgcn_s_barrier();                                                  \
  }

  for (int kk = 0; kk < KS2; kk += 2) {
    ITER(kk,     qA0, qA1, pA0, pA1);
    ITER(kk + 1, pA0, pA1, qA0, qA1);
  }
#undef ITER

  // ---- epilogue smem carved out of Ab (all reads drained past final barrier) ---
  float* eb = (float*)&Ab[0][0];
  float (*sc_part)[8] = (float (*)[8])eb;    // 64 x 8
  float* weight       = eb + 512;            // 64

  // ---- add b_enc, tanh-score partials (per wave: its 64 cols) ----
  float dpv[4], wfv[4], bev[4];
#pragma unroll
  for (int nf = 0; nf < 4; nf++) {
    const int c = wn * 64 + nf * 16 + arow;
    dpv[nf] = dp[b * AD + c];
    wfv[nf] = Wf[c];
    bev[nf] = b_enc[c];
  }
#pragma unroll
  for (int mf = 0; mf < 4; mf++) {
#pragma unroll
    for (int r = 0; r < 4; r++) {
      float p = 0.f;
#pragma unroll
      for (int nf = 0; nf < 4; nf++) {
        float e = acc[mf][nf][r] + bev[nf];
        acc[mf][nf][r] = e;                    // keep enc_proj (+b_enc) for o-accum
        float x = e + dpv[nf];
        float ex = __expf(2.f * x);            // tanh via exp
        float th = 1.f - 2.f / (ex + 1.f);
        p = fmaf(th, wfv[nf], p);
      }
      p += __shfl_xor(p, 1); p += __shfl_xor(p, 2);
      p += __shfl_xor(p, 4); p += __shfl_xor(p, 8);
      if (arow == 0) sc_part[mf * 16 + akg * 4 + r][wn] = p;
    }
  }
  __syncthreads();

  // ---- chunk softmax stats: all 64 rows in wave 0 ----
  if (t < BM) {
    float s = sc_part[t][0] + sc_part[t][1] + sc_part[t][2] + sc_part[t][3]
            + sc_part[t][4] + sc_part[t][5] + sc_part[t][6] + sc_part[t][7];
    raw_scores[(size_t)b * LL + l0 + t] = s;   // raw; finalize normalizes in place
    float m = s;
#pragma unroll
    for (int off = 1; off < 64; off <<= 1) m = fmaxf(m, __shfl_xor(m, off));
    float w = __expf(s - m);
    weight[t] = w;
    float ss = w;
#pragma unroll
    for (int off = 1; off < 64; off <<= 1) ss += __shfl_xor(ss, off);
    if (t == 0) {
      ws_ms[(b * NCH + chunk) * 2]     = m;
      ws_ms[(b * NCH + chunk) * 2 + 1] = ss;
    }
  }
  __syncthreads();

  // ---- o partial: weighted sum of enc_proj over the 64 rows ----
  float wv[4][4];
#pragma unroll
  for (int mf = 0; mf < 4; mf++)
#pragma unroll
    for (int r = 0; r < 4; r++) wv[mf][r] = weight[mf * 16 + akg * 4 + r];
#pragma unroll
  for (int nf = 0; nf < 4; nf++) {
    float cp = 0.f;
#pragma unroll
    for (int mf = 0; mf < 4; mf++)
#pragma unroll
      for (int r = 0; r < 4; r++) cp = fmaf(wv[mf][r], acc[mf][nf][r], cp);
    cp += __shfl_xor(cp, 16);
    cp += __shfl_xor(cp, 32);
    if (lane < 16)
      ws_o[((size_t)b * NCH + chunk) * AD + wn * 64 + nf * 16 + lane] = cp;
  }
}

// ---------------- kernel 2: finalize (merge chunk partials, normalize) ----------
__global__ __launch_bounds__(256) void finalize_kernel(
    const float* __restrict__ ws_ms, const float* __restrict__ ws_o,
    float* __restrict__ out0, float* __restrict__ outS) {
  const int b = blockIdx.x, t = threadIdx.x;
  float ms[NCH], ss[NCH];
  float M = -1e30f;
#pragma unroll
  for (int i = 0; i < NCH; i++) {
    ms[i] = ws_ms[(b * NCH + i) * 2];
    ss[i] = ws_ms[(b * NCH + i) * 2 + 1];
    M = fmaxf(M, ms[i]);
  }
  float S = 0.f, w[NCH];
#pragma unroll
  for (int i = 0; i < NCH; i++) { w[i] = __expf(ms[i] - M); S = fmaf(ss[i], w[i], S); }
  const float invS = 1.f / S;
  for (int c = t; c < AD; c += 256) {
    float a = 0.f;
#pragma unroll
    for (int i = 0; i < NCH; i++) a = fmaf(ws_o[((size_t)b * NCH + i) * AD + c], w[i], a);
    out0[b * AD + c] = a * invS;
  }
  for (int l = t; l < LL; l += 256) {
    float r = outS[(size_t)b * LL + l];
    outS[(size_t)b * LL + l] = __expf(r - M) * invS;
  }
}

extern "C" void kernel_launch(void* const* d_in, const int* in_sizes, int n_in,
                              void* d_out, int out_size, void* d_ws, size_t ws_size,
                              hipStream_t stream) {
  const float* sem    = (const float*)d_in[0];
  const float* dec    = (const float*)d_in[1];
  const float* W_enc  = (const float*)d_in[2];
  const float* b_enc  = (const float*)d_in[3];
  const float* W_dec  = (const float*)d_in[4];
  const float* b_dec  = (const float*)d_in[5];
  const float* W_full = (const float*)d_in[6];
  // d_in[7] = b_full: constant shift, cancels in softmax.

  float* out0 = (float*)d_out;            // att_output [64][512]
  float* outS = out0 + BB * AD;           // att_scores [64][2048]

  char* ws = (char*)d_ws;
  unsigned short* Wb = (unsigned short*)ws;                          // 1 MB bf16 packed W_enc
  float* dpw   = (float*)(ws + (1 << 20));                           // 128 KB dec_proj+b_dec
  float* ws_ms = (float*)(ws + (1 << 20) + (128 << 10));             // 16 KB (m,s) per chunk
  float* ws_o  = (float*)(ws + (1 << 20) + (144 << 10));             // 4 MB o partials

  prep_kernel<<<BB + 128, 512, 0, stream>>>(W_enc, dec, W_dec, b_dec, Wb, dpw);
  dim3 g1(NCH, BB);
  fused_kernel<<<g1, 512, 0, stream>>>(sem, Wb, dpw, b_enc, W_full, outS, ws_ms, ws_o);
  finalize_kernel<<<BB, 256, 0, stream>>>(ws_ms, ws_o, out0, outS);
}